// Round 1
// baseline (119.670 us; speedup 1.0000x reference)
//
#include <hip/hip_runtime.h>

// DecodePredictions: YOLO-style decode.
// inputs (d_in order from setup_inputs):
//   [0] images (16,640,640,3) f32  -- only shape matters (H=W=640)
//   [1] pred0  (16,80,80,85)  f32
//   [2] pred1  (16,40,40,85)  f32
//   [3] pred2  (16,20,20,85)  f32
// output: (16, 8400*80, 6) f32 = 64,512,000 floats
//
// Per anchor record for class c: [x1, y1, x2, y2, c, score_c]
//   x = (px+gx)*stride/640 ; y = (py+gy)*stride/640
//   w = exp(pw)*stride/640 ; h = exp(ph)*stride/640
//   x1=x*640, y1=y*640, x2=(x+w)*640, y2=(y+h)*640
//   score_c = sigmoid(pobj)*sigmoid(logit_c)

#define CLASSES 80
#define NANCH   8400      // 80*80 + 40*40 + 20*20
#define BATCH   16
#define IMG     640.0f

__device__ __forceinline__ float sigmoidf_(float v) {
    return 1.0f / (1.0f + expf(-v));
}

__global__ __launch_bounds__(256) void decode_kernel(
    const float* __restrict__ p0,
    const float* __restrict__ p1,
    const float* __restrict__ p2,
    float* __restrict__ out)
{
    const int lane   = threadIdx.x & 63;
    const int waveId = blockIdx.x * (blockDim.x >> 6) + (threadIdx.x >> 6);
    const int nWaves = gridDim.x * (blockDim.x >> 6);
    const int A = BATCH * NANCH;   // 134,400 anchors

    for (int a = waveId; a < A; a += nWaves) {
        const int b = a / NANCH;
        const int n = a - b * NANCH;

        const float* p;
        int s, local;
        float stridef;
        if (n < 6400) {        // level 0: 80x80, stride 8
            s = 80; local = n;
            p = p0 + ((size_t)b * 6400 + local) * 85;
            stridef = 8.0f;
        } else if (n < 8000) { // level 1: 40x40, stride 16
            s = 40; local = n - 6400;
            p = p1 + ((size_t)b * 1600 + local) * 85;
            stridef = 16.0f;
        } else {               // level 2: 20x20, stride 32
            s = 20; local = n - 8000;
            p = p2 + ((size_t)b * 400 + local) * 85;
            stridef = 32.0f;
        }
        const int gx = local % s;   // meshgrid 'xy': grid = (col, row)
        const int gy = local / s;

        const float px = p[0], py = p[1], pw = p[2], ph = p[3], pobj = p[4];
        const float inv = stridef / IMG;
        const float x = (px + (float)gx) * inv;
        const float y = (py + (float)gy) * inv;
        const float w = expf(pw) * inv;
        const float h = expf(ph) * inv;
        const float x1 = x * IMG;
        const float y1 = y * IMG;
        const float x2 = (x + w) * IMG;
        const float y2 = (y + h) * IMG;
        const float sobj = sigmoidf_(pobj);

        // 480 floats per anchor = 120 float4s; pattern repeats every 3 float4s:
        //   j%3==0 : [x1, y1, x2, y2]                      (class 2k, fields 0..3)
        //   j%3==1 : [2k, s_{2k}, x1, y1]                  (class 2k f4..5 | 2k+1 f0..1)
        //   j%3==2 : [x2, y2, 2k+1, s_{2k+1}]              (class 2k+1, fields 2..5)
        float4* ob = reinterpret_cast<float4*>(out) + (size_t)a * 120;

        #pragma unroll
        for (int it = 0; it < 2; ++it) {
            const int j = lane + it * 64;
            if (j < 120) {
                const int pair  = j / 3;
                const int phase = j - pair * 3;
                float4 v;
                if (phase == 0) {
                    v = make_float4(x1, y1, x2, y2);
                } else if (phase == 1) {
                    const int c = 2 * pair;
                    const float sc = sobj * sigmoidf_(p[5 + c]);
                    v = make_float4((float)c, sc, x1, y1);
                } else {
                    const int c = 2 * pair + 1;
                    const float sc = sobj * sigmoidf_(p[5 + c]);
                    v = make_float4(x2, y2, (float)c, sc);
                }
                ob[j] = v;
            }
        }
    }
}

extern "C" void kernel_launch(void* const* d_in, const int* in_sizes, int n_in,
                              void* d_out, int out_size, void* d_ws, size_t ws_size,
                              hipStream_t stream) {
    const float* p0 = (const float*)d_in[1];
    const float* p1 = (const float*)d_in[2];
    const float* p2 = (const float*)d_in[3];
    float* out = (float*)d_out;

    // 2100 blocks x 4 waves = 8400 waves; each wave handles 16 anchors.
    decode_kernel<<<2100, 256, 0, stream>>>(p0, p1, p2, out);
}

// Round 2
// 90.896 us; speedup vs baseline: 1.3166x; 1.3166x over previous
//
#include <hip/hip_runtime.h>

// DecodePredictions: YOLO-style decode, flat one-thread-per-float4 layout.
// inputs (d_in order from setup_inputs):
//   [0] images (16,640,640,3) f32  -- only shape matters (H=W=640)
//   [1] pred0  (16,80,80,85)  f32
//   [2] pred1  (16,40,40,85)  f32
//   [3] pred2  (16,20,20,85)  f32
// output: (16, 8400*80, 6) f32 = 64,512,000 floats = 16,128,000 float4
//
// Output record per (anchor, class c): [x1, y1, x2, y2, c, score_c]
// 6 floats * 80 classes = 480 floats = 120 float4 per anchor; the 6-float
// record pattern repeats every 3 float4 (covers classes 2k, 2k+1):
//   phase 0: [x1, y1, x2, y2]          (class 2k fields 0..3)
//   phase 1: [2k, s_2k, x1, y1]        (class 2k fields 4..5 | class 2k+1 fields 0..1)
//   phase 2: [x2, y2, 2k+1, s_2k+1]    (class 2k+1 fields 2..5)

#define NANCH   8400      // 80*80 + 40*40 + 20*20
#define IMG     640.0f

__device__ __forceinline__ float sigmoidf_(float v) {
    return 1.0f / (1.0f + expf(-v));
}

__global__ __launch_bounds__(256) void decode_kernel(
    const float* __restrict__ p0,
    const float* __restrict__ p1,
    const float* __restrict__ p2,
    float* __restrict__ out,
    unsigned nF4)
{
    const unsigned t = blockIdx.x * 256u + threadIdx.x;  // global float4 index
    if (t >= nF4) return;

    const unsigned a = t / 120u;          // anchor index in [0, 134400)
    const unsigned j = t - a * 120u;      // float4 slot within anchor [0,120)
    const unsigned b = a / NANCH;
    const unsigned n = a - b * NANCH;

    const float* p;
    unsigned s, local;
    float stridef;
    if (n < 6400u) {        // level 0: 80x80, stride 8
        s = 80u; local = n;
        p = p0 + ((size_t)b * 6400u + local) * 85u;
        stridef = 8.0f;
    } else if (n < 8000u) { // level 1: 40x40, stride 16
        s = 40u; local = n - 6400u;
        p = p1 + ((size_t)b * 1600u + local) * 85u;
        stridef = 16.0f;
    } else {                // level 2: 20x20, stride 32
        s = 20u; local = n - 8000u;
        p = p2 + ((size_t)b * 400u + local) * 85u;
        stridef = 32.0f;
    }
    const unsigned gx = local % s;   // meshgrid 'xy': grid = (col, row)
    const unsigned gy = local / s;

    const unsigned pair  = j / 3u;
    const unsigned phase = j - pair * 3u;

    // Independent loads — all issue before any use.
    const float px = p[0], py = p[1], pw = p[2], ph = p[3];
    const float inv = stridef * (1.0f / IMG);
    const float x = (px + (float)gx) * inv;
    const float y = (py + (float)gy) * inv;
    const float w = expf(pw) * inv;
    const float h = expf(ph) * inv;
    const float x1 = x * IMG;
    const float y1 = y * IMG;
    const float x2 = (x + w) * IMG;
    const float y2 = (y + h) * IMG;

    float4 v;
    if (phase == 0u) {
        v = make_float4(x1, y1, x2, y2);
    } else {
        const float    pobj = p[4];
        const unsigned c    = 2u * pair + (phase == 2u ? 1u : 0u);
        const float    sc   = sigmoidf_(pobj) * sigmoidf_(p[5u + c]);
        if (phase == 1u) v = make_float4((float)c, sc, x1, y1);
        else             v = make_float4(x2, y2, (float)c, sc);
    }

    reinterpret_cast<float4*>(out)[t] = v;
}

extern "C" void kernel_launch(void* const* d_in, const int* in_sizes, int n_in,
                              void* d_out, int out_size, void* d_ws, size_t ws_size,
                              hipStream_t stream) {
    const float* p0 = (const float*)d_in[1];
    const float* p1 = (const float*)d_in[2];
    const float* p2 = (const float*)d_in[3];
    float* out = (float*)d_out;

    const unsigned nF4 = (unsigned)(out_size / 4);        // 16,128,000
    const unsigned blocks = (nF4 + 255u) / 256u;          // 63,000
    decode_kernel<<<blocks, 256, 0, stream>>>(p0, p1, p2, out, nF4);
}

// Round 4
// 56.465 us; speedup vs baseline: 2.1194x; 1.6098x over previous
//
#include <hip/hip_runtime.h>

// DecodePredictions: YOLO-style decode, two-stage.
//   Stage A: one thread per anchor (134,400) -> 32B record in d_ws:
//            [x1, y1, x2, y2, sobj, bits(level), bits(elem_offset), 0]
//   Stage B: one thread per output float4 (16,128,000) -> decode record + logit.
//
// inputs (d_in order from setup_inputs):
//   [0] images (16,640,640,3) f32  -- only shape matters (H=W=640)
//   [1] pred0  (16,80,80,85)  f32
//   [2] pred1  (16,40,40,85)  f32
//   [3] pred2  (16,20,20,85)  f32
// output: (16, 8400*80, 6) f32 = 64,512,000 floats = 16,128,000 float4
//
// Record pattern per anchor: 120 float4, repeating every 3:
//   phase 0: [x1, y1, x2, y2]
//   phase 1: [2k, s_2k, x1, y1]
//   phase 2: [x2, y2, 2k+1, s_2k+1]

#define NANCH   8400      // 80*80 + 40*40 + 20*20
#define BATCH   16
#define NA      (BATCH * NANCH)   // 134,400 anchors
#define IMG     640.0f

// clang-native float4 (accepted by __builtin_nontemporal_store)
typedef float vf4 __attribute__((ext_vector_type(4)));

__device__ __forceinline__ float sigmoidf_(float v) {
    return 1.0f / (1.0f + expf(-v));
}

// ---------------- Stage A: per-anchor decode ----------------
__global__ __launch_bounds__(256) void anchor_kernel(
    const float* __restrict__ p0,
    const float* __restrict__ p1,
    const float* __restrict__ p2,
    vf4* __restrict__ ws)   // 2 vf4 per anchor
{
    const unsigned i = blockIdx.x * 256u + threadIdx.x;
    if (i >= NA) return;

    const unsigned b = i / NANCH;           // constant divisor -> magic mul
    const unsigned n = i - b * NANCH;

    const float* p;
    unsigned lvl, elem, gx, gy;
    float stridef;
    if (n < 6400u) {            // 80x80, stride 8
        const unsigned loc = n;
        lvl = 0u; gx = loc % 80u; gy = loc / 80u;
        elem = (b * 6400u + loc) * 85u;
        p = p0; stridef = 8.0f;
    } else if (n < 8000u) {     // 40x40, stride 16
        const unsigned loc = n - 6400u;
        lvl = 1u; gx = loc % 40u; gy = loc / 40u;
        elem = (b * 1600u + loc) * 85u;
        p = p1; stridef = 16.0f;
    } else {                    // 20x20, stride 32
        const unsigned loc = n - 8000u;
        lvl = 2u; gx = loc % 20u; gy = loc / 20u;
        elem = (b * 400u + loc) * 85u;
        p = p2; stridef = 32.0f;
    }
    p += elem;

    const float px = p[0], py = p[1], pw = p[2], ph = p[3], pobj = p[4];
    const float inv = stridef * (1.0f / IMG);
    const float x = (px + (float)gx) * inv;
    const float y = (py + (float)gy) * inv;
    const float w = expf(pw) * inv;
    const float h = expf(ph) * inv;

    vf4 box; box.x = x * IMG; box.y = y * IMG; box.z = (x + w) * IMG; box.w = (y + h) * IMG;
    vf4 aux; aux.x = sigmoidf_(pobj);
    aux.y = __uint_as_float(lvl);
    aux.z = __uint_as_float(elem);
    aux.w = 0.0f;
    ws[(size_t)i * 2u]      = box;
    ws[(size_t)i * 2u + 1u] = aux;
}

// ---------------- Stage B: output writer ----------------
__global__ __launch_bounds__(256) void write_kernel(
    const float* __restrict__ p0,
    const float* __restrict__ p1,
    const float* __restrict__ p2,
    const vf4* __restrict__ ws,
    vf4* __restrict__ out)
{
    const unsigned t = blockIdx.x * 256u + threadIdx.x;   // float4 index
    const unsigned a = t / 120u;                          // anchor (magic mul)
    const unsigned j = t - a * 120u;
    const unsigned pair  = j / 3u;
    const unsigned phase = j - pair * 3u;

    const vf4 box = ws[(size_t)a * 2u];

    vf4 v;
    if (phase == 0u) {
        v = box;
    } else {
        const vf4 aux  = ws[(size_t)a * 2u + 1u];
        const unsigned lvl  = __float_as_uint(aux.y);
        const unsigned elem = __float_as_uint(aux.z);
        const float* p = (lvl == 0u) ? p0 : ((lvl == 1u) ? p1 : p2);
        const unsigned c = 2u * pair + (phase == 2u ? 1u : 0u);
        const float sc = aux.x * sigmoidf_(p[elem + 5u + c]);
        if (phase == 1u) { v.x = (float)c; v.y = sc;  v.z = box.x;   v.w = box.y; }
        else             { v.x = box.z;    v.y = box.w; v.z = (float)c; v.w = sc; }
    }

    __builtin_nontemporal_store(v, &out[t]);
}

// ---------------- Fallback single kernel (if ws too small) ----------------
__global__ __launch_bounds__(256) void decode_flat_kernel(
    const float* __restrict__ p0,
    const float* __restrict__ p1,
    const float* __restrict__ p2,
    float* __restrict__ out,
    unsigned nF4)
{
    const unsigned t = blockIdx.x * 256u + threadIdx.x;
    if (t >= nF4) return;
    const unsigned a = t / 120u;
    const unsigned j = t - a * 120u;
    const unsigned b = a / NANCH;
    const unsigned n = a - b * NANCH;

    const float* p;
    unsigned s, local;
    float stridef;
    if (n < 6400u) { s = 80u; local = n;        p = p0 + ((size_t)b * 6400u + local) * 85u; stridef = 8.0f; }
    else if (n < 8000u) { s = 40u; local = n - 6400u; p = p1 + ((size_t)b * 1600u + local) * 85u; stridef = 16.0f; }
    else { s = 20u; local = n - 8000u; p = p2 + ((size_t)b * 400u + local) * 85u; stridef = 32.0f; }
    const unsigned gx = local % s;
    const unsigned gy = local / s;
    const unsigned pair  = j / 3u;
    const unsigned phase = j - pair * 3u;

    const float px = p[0], py = p[1], pw = p[2], ph = p[3];
    const float inv = stridef * (1.0f / IMG);
    const float x = (px + (float)gx) * inv;
    const float y = (py + (float)gy) * inv;
    const float w = expf(pw) * inv;
    const float h = expf(ph) * inv;
    const float x1 = x * IMG, y1 = y * IMG, x2 = (x + w) * IMG, y2 = (y + h) * IMG;

    float4 v;
    if (phase == 0u) v = make_float4(x1, y1, x2, y2);
    else {
        const unsigned c = 2u * pair + (phase == 2u ? 1u : 0u);
        const float sc = sigmoidf_(p[4]) * sigmoidf_(p[5u + c]);
        if (phase == 1u) v = make_float4((float)c, sc, x1, y1);
        else             v = make_float4(x2, y2, (float)c, sc);
    }
    reinterpret_cast<float4*>(out)[t] = v;
}

extern "C" void kernel_launch(void* const* d_in, const int* in_sizes, int n_in,
                              void* d_out, int out_size, void* d_ws, size_t ws_size,
                              hipStream_t stream) {
    const float* p0 = (const float*)d_in[1];
    const float* p1 = (const float*)d_in[2];
    const float* p2 = (const float*)d_in[3];

    const unsigned nF4 = (unsigned)(out_size / 4);        // 16,128,000
    const size_t ws_needed = (size_t)NA * 32u;            // 4,300,800 B

    if (ws_size >= ws_needed) {
        vf4* ws = (vf4*)d_ws;
        anchor_kernel<<<(NA + 255u) / 256u, 256, 0, stream>>>(p0, p1, p2, ws);
        write_kernel<<<nF4 / 256u, 256, 0, stream>>>(p0, p1, p2, ws, (vf4*)d_out);
    } else {
        decode_flat_kernel<<<(nF4 + 255u) / 256u, 256, 0, stream>>>(
            p0, p1, p2, (float*)d_out, nF4);
    }
}